// Round 5
// baseline (753.463 us; speedup 1.0000x reference)
//
#include <hip/hip_runtime.h>

// ---------------- constants ----------------
#define B_    64
#define CIN   64
#define CH    256
#define T_    2048
#define NP    10
#define INVLN2 1.44269504088896340736f
#define INFV  1e10f
#define FPAD  16          // front-pad rows of diag buffers
#define DROWS 2088        // diag rows incl pads
#define SDIAG 33408       // DROWS*16 per batch
#define BFPAD 16
#define BKROWS 2096       // per-batch b rows incl pads

// d_out element offsets (float32)
static const size_t DO_H   = 0;
static const size_t DO_OUT = 33554432;
static const size_t DO_ENS = 33555072;
static const size_t DO_ONE = 34046592;   // holds out2 raw sums -> means -> "one"
static const size_t DO_OP  = 34210432;
static const size_t DO_ATT = 34210433;

// d_ws element offsets (float32)
static const size_t OFF_D2 = 0;          // [64][2088][16] diag layout
static const size_t OFF_RF = 2138112;    // [64][2088][16] forward R'
static const size_t OFF_Q  = 4276224;    // [64][2088][16] reverse Q = R~' - D'
static const size_t OFF_BK = 6414336;    // [64][2096] diag-min keys -> floats; later z1/z2
static const size_t OFF_RS = 6548480;    // [64][16] rowsums (zeroed)
static const size_t OFF_RT = 6549504;    // [64] rtot'
static const size_t OFF_O1 = 6549568;    // [64][256] out1 means
static const size_t OFF_O3 = 6565952;    // [64][256][10] out3 raw (zeroed)
static const size_t OFF_IND= 6729792;    // [0]=ind sum (zeroed)
static const size_t WS_END = 6729808;    // 26.92 MB

// lane i <- lane i-1 within 16-lane row; shifted-in lanes get INFV
__device__ __forceinline__ float dpp_shr1_inf(float x) {
  return __int_as_float(__builtin_amdgcn_update_dpp(
      __float_as_int(INFV), __float_as_int(x), 0x111, 0xf, 0xf, false));
}
// lane i <- lane i-1 within 16-lane row; shifted-in lanes get 0
__device__ __forceinline__ float dpp_shr1_z(float x) {
  return __int_as_float(__builtin_amdgcn_update_dpp(0, __float_as_int(x), 0x111, 0xf, 0xf, true));
}
// 16-lane row prefix sum; lane 15 of each row holds the row total
__device__ __forceinline__ float row_prefix_sum16(float v) {
  v += __int_as_float(__builtin_amdgcn_update_dpp(0, __float_as_int(v), 0x111, 0xf, 0xf, true));
  v += __int_as_float(__builtin_amdgcn_update_dpp(0, __float_as_int(v), 0x112, 0xf, 0xf, true));
  v += __int_as_float(__builtin_amdgcn_update_dpp(0, __float_as_int(v), 0x114, 0xf, 0xf, true));
  v += __int_as_float(__builtin_amdgcn_update_dpp(0, __float_as_int(v), 0x118, 0xf, 0xf, true));
  return v;
}
__device__ __forceinline__ unsigned fkey(float f) {
  unsigned u = __float_as_uint(f);
  return (u & 0x80000000u) ? ~u : (u | 0x80000000u);
}

// ---------------- K1: h = relu(conv_w @ x + b), fused STP raw segment sums ----------------
__global__ __launch_bounds__(256) void k1_conv(const float* __restrict__ x, const float* __restrict__ w,
                                               const float* __restrict__ bias, float* __restrict__ h,
                                               float* __restrict__ out2w) {
  const int tt = blockIdx.x, ot = blockIdx.y, b = blockIdx.z;
  const int tid = threadIdx.x;
  __shared__ float xs[64][132];
  __shared__ float wt[64][64];
  const int t0 = tt * 128, o0 = ot * 64;
  {
    const float* xb = x + ((size_t)b * CIN) * T_ + t0;
#pragma unroll
    for (int k = 0; k < 8; ++k) {
      int idx = tid + k * 256;
      int c = idx >> 5, q = idx & 31;
      float4 v = *(const float4*)(xb + (size_t)c * T_ + q * 4);
      *(float4*)(&xs[c][q * 4]) = v;
    }
#pragma unroll
    for (int k = 0; k < 4; ++k) {
      int idx = tid + k * 256;
      int o = idx >> 4, c4 = (idx & 15) * 4;
      float4 v = *(const float4*)(w + (size_t)(o0 + o) * 64 + c4);
      wt[c4 + 0][o] = v.x; wt[c4 + 1][o] = v.y; wt[c4 + 2][o] = v.z; wt[c4 + 3][o] = v.w;
    }
  }
  __syncthreads();
  const int og = tid >> 4, tg = tid & 15;
  float acc[4][8];
#pragma unroll
  for (int i = 0; i < 4; ++i)
#pragma unroll
    for (int j = 0; j < 8; ++j) acc[i][j] = 0.f;
  for (int c = 0; c < 64; ++c) {
    float a0 = wt[c][og * 4 + 0], a1 = wt[c][og * 4 + 1], a2 = wt[c][og * 4 + 2], a3 = wt[c][og * 4 + 3];
    float xv[8];
#pragma unroll
    for (int j = 0; j < 8; ++j) xv[j] = xs[c][tg * 8 + j];
#pragma unroll
    for (int j = 0; j < 8; ++j) {
      acc[0][j] += a0 * xv[j]; acc[1][j] += a1 * xv[j];
      acc[2][j] += a2 * xv[j]; acc[3][j] += a3 * xv[j];
    }
  }
  // segment geometry
  const int tb = t0 + tg * 8;
  int s_lo = tb / 204; if (s_lo > 9) s_lo = 9;
  int s_hi = (tb + 7) / 204; if (s_hi > 9) s_hi = 9;
  const int cross = (s_hi > s_lo) ? ((s_lo + 1) * 204 - tb) : 8;
  int sblock = t0 / 204; if (sblock > 9) sblock = 9;
  const bool crossB = (sblock < 9) && ((sblock + 1) * 204 < t0 + 128);

  float* hb = h + ((size_t)b * CH + o0) * T_ + t0;
#pragma unroll
  for (int i = 0; i < 4; ++i) {
    const float bv = bias[o0 + og * 4 + i];
    float vs[8];
#pragma unroll
    for (int j = 0; j < 8; ++j) vs[j] = fmaxf(acc[i][j] + bv, 0.f);
    float4 v0, v1;
    v0.x = vs[0]; v0.y = vs[1]; v0.z = vs[2]; v0.w = vs[3];
    v1.x = vs[4]; v1.y = vs[5]; v1.z = vs[6]; v1.w = vs[7];
    *(float4*)(&hb[(size_t)(og * 4 + i) * T_ + tg * 8]) = v0;
    *(float4*)(&hb[(size_t)(og * 4 + i) * T_ + tg * 8 + 4]) = v1;
    float sumA = 0.f, sumB = 0.f;
#pragma unroll
    for (int j = 0; j < 8; ++j) { if (j < cross) sumA += vs[j]; else sumB += vs[j]; }
    float cLo = ((s_lo == sblock) ? sumA : 0.f) + ((s_hi == sblock) ? sumB : 0.f);
    float cHi = ((s_lo == sblock + 1) ? sumA : 0.f) + ((s_hi == sblock + 1) ? sumB : 0.f);
    float rLo = row_prefix_sum16(cLo);
    float rHi = row_prefix_sum16(cHi);
    if (tg == 15) {
      float* o2p = out2w + ((size_t)(b * CH + o0 + og * 4 + i)) * NP;
      atomicAdd(o2p + sblock, rLo);
      if (crossB) atomicAdd(o2p + sblock + 1, rHi);
    }
  }
}

// ---------------- K2: D2diag[d][p] (log2-scaled) + per-diagonal min keys ----------------
__global__ __launch_bounds__(256) void k2_d2(const float* __restrict__ h, const float* __restrict__ protos,
                                             float* __restrict__ D2g, unsigned* __restrict__ bkey) {
  const int tt = blockIdx.x, b = blockIdx.y, tid = threadIdx.x;
  __shared__ float pl[2560];
  __shared__ float pn[NP];
  __shared__ unsigned smin[272];
#pragma unroll
  for (int k = 0; k < 10; ++k) pl[tid + k * 256] = protos[tid + k * 256];
  for (int i = tid; i < 272; i += 256) smin[i] = 0xFFFFFFFFu;
  __syncthreads();
  if (tid < NP) {
    float s = 0.f;
    for (int c = 0; c < CH; ++c) { float v = pl[c * NP + tid]; s += v * v; }
    pn[tid] = s;
  }
  __syncthreads();
  const int t0 = tt * 256;
  const int t = t0 + tid;
  const float* hb = h + (size_t)b * CH * T_ + t;
  float hn = 0.f, ph[NP];
#pragma unroll
  for (int p = 0; p < NP; ++p) ph[p] = 0.f;
  for (int c = 0; c < CH; ++c) {
    float hv = hb[(size_t)c * T_];
    hn += hv * hv;
#pragma unroll
    for (int p = 0; p < NP; ++p) ph[p] += pl[c * NP + p] * hv;
  }
  float* dst = D2g + (size_t)b * SDIAG + FPAD * 16;
#pragma unroll
  for (int p = 0; p < NP; ++p) {
    float dv = (pn[p] + hn - 2.f * ph[p]) * INVLN2;
    dst[(t + p) * 16 + p] = dv;
    atomicMin(&smin[tid + p], fkey(dv));
  }
  __syncthreads();
  unsigned* bk = bkey + (size_t)b * BKROWS + BFPAD + t0;
  for (int i = tid; i < 265; i += 256) atomicMin(&bk[i], smin[i]);
}

// ---------------- K3b: decode b keys; finalize out1/out2 means ----------------
__global__ __launch_bounds__(256) void k3b_fin(float* __restrict__ out2w, float* __restrict__ out1w,
                                               unsigned* __restrict__ bkey) {
  const int b = blockIdx.x, o = threadIdx.x;
  unsigned* bk = bkey + (size_t)b * BKROWS;
  for (int i = o; i < BKROWS; i += 256) {
    unsigned u = bk[i];
    float f = (u & 0x80000000u) ? __uint_as_float(u ^ 0x80000000u) : __uint_as_float(~u);
    ((float*)bk)[i] = f;
  }
  float* p = out2w + ((size_t)(b * CH + o)) * NP;
  float vals[NP], tot = 0.f;
#pragma unroll
  for (int s = 0; s < NP; ++s) { vals[s] = p[s]; tot += vals[s]; }
  out1w[b * CH + o] = tot * (1.f / 2048.f);
#pragma unroll
  for (int s = 0; s < 9; ++s) p[s] = vals[s] * (1.f / 204.f);
  p[9] = vals[9] * (1.f / 212.f);
}

// ---------------- K4: bidirectional soft-DTW DP, 2 ILP chains per lane ----------------
// Wave layout: grp = lane>>4 in {0:fwd bA0, 1:rev bA0, 2:fwd bA1, 3:rev bA1}; each lane
// additionally runs a SECOND chain (batches +2) interleaved in registers -> 4 batches/wave,
// grid = 16 blocks. (m,e) rep: y = m - log2(e); per-diagonal baseline b_d subtracted.
// Both directions store at ascending [step][lane] positions; k5 un-reverses via indexing.
struct DPState { float m1, e1, amP, aeP, bP; };
__device__ __forceinline__ float dp_step(DPState& s, float cD, float bv, bool isB) {
  float a_m = dpp_shr1_inf(s.m1);
  float a_e = dpp_shr1_z(s.e1);
  float c_m = s.amP - s.bP;                        // diag d-2, re-shifted by b_{d-1}
  float mt = fminf(fminf(a_m, s.m1), c_m);
  float e = __builtin_amdgcn_exp2f(mt - a_m) * a_e
          + __builtin_amdgcn_exp2f(mt - s.m1) * s.e1
          + __builtin_amdgcn_exp2f(mt - c_m) * s.aeP;
  float m = mt + cD;
  float y = m - __builtin_amdgcn_logf(e);          // native log2
  s.amP = a_m; s.aeP = a_e; s.bP = bv;
  s.m1 = m; s.e1 = e;
  return isB ? (y - cD) : y;
}

__global__ __launch_bounds__(64, 1) void k4_dp(const float* __restrict__ D2g, const float* __restrict__ bg,
                                               float* __restrict__ Rfg, float* __restrict__ Qg,
                                               float* __restrict__ rtotg) {
  const int l = threadIdx.x;
  const int grp = l >> 4, lr = l & 15;
  const bool isB = (grp & 1) != 0;
  const int elem  = isB ? (9 - lr) : lr;
  const int dstep = isB ? -16 : 16;      // element step per diagonal (loads)
  const int bstep = isB ? -1 : 1;
  const int ld0   = isB ? (FPAD + 2056) * 16 : FPAD * 16;
  const int lb0   = isB ? (BFPAD + 2056) : BFPAD;

  const float* pD0; const float* pD1;
  const float* pB0; const float* pB1;
  float* pS0; float* pS1;
  int bat0, bat1;
  {
    bat0 = (blockIdx.x << 2) + (grp >> 1);
    bat1 = bat0 + 2;
    pD0 = D2g + (size_t)bat0 * SDIAG + ld0 + elem;
    pD1 = D2g + (size_t)bat1 * SDIAG + ld0 + elem;
    pB0 = bg + (size_t)bat0 * BKROWS + lb0;
    pB1 = bg + (size_t)bat1 * BKROWS + lb0;
    float* Sbase = isB ? Qg : Rfg;
    pS0 = Sbase + (size_t)bat0 * SDIAG + FPAD * 16 + lr;
    pS1 = Sbase + (size_t)bat1 * SDIAG + FPAD * 16 + lr;
  }
  DPState stA, stB;
  { // d = 0
    float D0 = pD0[0], b0 = pB0[0];
    float D1 = pD1[0], b1 = pB1[0];
    stA.m1 = (lr == 0) ? (D0 - b0) : INFV; stA.e1 = 1.f;
    stA.amP = INFV; stA.aeP = 1.f; stA.bP = b0;
    stB.m1 = (lr == 0) ? (D1 - b1) : INFV; stB.e1 = 1.f;
    stB.amP = INFV; stB.aeP = 1.f; stB.bP = b1;
    pS0[0] = stA.m1;
    pS1[0] = stB.m1;
  }
  // prologue d = 1..15 (masked)
  {
    const float* qD0 = pD0; const float* qD1 = pD1;
    const float* qB0 = pB0; const float* qB1 = pB1;
#pragma unroll
    for (int d = 1; d < 16; ++d) {
      qD0 += dstep; qB0 += bstep; qD1 += dstep; qB1 += bstep;
      float Dv0 = qD0[0], bv0 = qB0[0];
      float Dv1 = qD1[0], bv1 = qB1[0];
      float sv0 = dp_step(stA, Dv0 - bv0, bv0, isB);
      float sv1 = dp_step(stB, Dv1 - bv1, bv1, isB);
      if (lr > d) { stA.m1 = INFV; stA.e1 = 1.f; stB.m1 = INFV; stB.e1 = 1.f; }
      pS0[d * 16] = sv0;
      pS1[d * 16] = sv1;
    }
  }
  // prefill cur (d=16..23) and n1 (d=24..31); pointers end at d=32
  float cA[8], bA[8], n1DA[8], n1BA[8];
  float cB[8], bB[8], n1DB[8], n1BB[8];
  {
    const float* qD0 = pD0 + 16 * dstep; const float* qB0 = pB0 + 16 * bstep;
    const float* qD1 = pD1 + 16 * dstep; const float* qB1 = pB1 + 16 * bstep;
#pragma unroll
    for (int j = 0; j < 8; ++j) {
      float Dv0 = qD0[0], bv0 = qB0[0]; cA[j] = Dv0 - bv0; bA[j] = bv0; qD0 += dstep; qB0 += bstep;
      float Dv1 = qD1[0], bv1 = qB1[0]; cB[j] = Dv1 - bv1; bB[j] = bv1; qD1 += dstep; qB1 += bstep;
    }
#pragma unroll
    for (int j = 0; j < 8; ++j) {
      n1DA[j] = qD0[0]; n1BA[j] = qB0[0]; qD0 += dstep; qB0 += bstep;
      n1DB[j] = qD1[0]; n1BB[j] = qB1[0]; qD1 += dstep; qB1 += bstep;
    }
    pD0 = qD0; pB0 = qB0; pD1 = qD1; pB1 = qB1;
    pS0 += 256; pS1 += 256;               // store base -> d=16
  }
  // main loop d = 16..2055 in blocks of 8, distance-2 prefetch
#pragma unroll 1
  for (int d0 = 16; d0 <= 2048; d0 += 8) {
    float n2DA[8], n2BA[8], n2DB[8], n2BB[8];
    if (d0 <= 2032) {
#pragma unroll
      for (int j = 0; j < 8; ++j) {
        n2DA[j] = pD0[0]; n2BA[j] = pB0[0]; pD0 += dstep; pB0 += bstep;
        n2DB[j] = pD1[0]; n2BB[j] = pB1[0]; pD1 += dstep; pB1 += bstep;
      }
    }
#pragma unroll
    for (int j = 0; j < 8; ++j) {
      float sv0 = dp_step(stA, cA[j], bA[j], isB);
      float sv1 = dp_step(stB, cB[j], bB[j], isB);
      pS0[j * 16] = sv0;
      pS1[j * 16] = sv1;
    }
    pS0 += 128; pS1 += 128;
#pragma unroll
    for (int j = 0; j < 8; ++j) {
      cA[j] = n1DA[j] - n1BA[j]; bA[j] = n1BA[j]; n1DA[j] = n2DA[j]; n1BA[j] = n2BA[j];
      cB[j] = n1DB[j] - n1BB[j]; bB[j] = n1BB[j]; n1DB[j] = n2DB[j]; n1BB[j] = n2BB[j];
    }
  }
  // final step d = 2056 (pointers sit exactly at d=2056 after 253 load-blocks)
  {
    float Dv0 = pD0[0], bv0 = pB0[0];
    float Dv1 = pD1[0], bv1 = pB1[0];
    float sv0 = dp_step(stA, Dv0 - bv0, bv0, isB);
    float sv1 = dp_step(stB, Dv1 - bv1, bv1, isB);
    pS0[0] = sv0;
    pS1[0] = sv1;
    if (lr == 9 && !isB) { rtotg[bat0] = sv0; rtotg[bat1] = sv1; }
  }
}

// ---------------- K5: E = exp2(rtot - Rf' - Q); rowsums; out3raw GEMM ----------------
__global__ __launch_bounds__(256) void k5_out3(const float* __restrict__ h, const float* __restrict__ Rfg,
                                               const float* __restrict__ Qg, const float* __restrict__ rtotg,
                                               float* __restrict__ out3raw, float* __restrict__ rowsumg) {
  const int tc = blockIdx.x, b = blockIdx.y, tid = threadIdx.x;
  const int t0 = tc * 128;
  __shared__ float Rfs[2304];
  __shared__ float Qs[2304];
  __shared__ float Es[2048];
  __shared__ float rsl[272];
  const float* Rfb = Rfg + (size_t)b * SDIAG + (size_t)(FPAD + t0) * 16;
  const int qlo = 2056 - t0 - 143;
  const float* Qb = Qg + (size_t)b * SDIAG + (size_t)(FPAD + qlo) * 16;
#pragma unroll
  for (int k = 0; k < 3; ++k) {
    int i4 = tid + k * 256;
    if (i4 < 576) {
      ((float4*)Rfs)[i4] = ((const float4*)Rfb)[i4];
      ((float4*)Qs)[i4]  = ((const float4*)Qb)[i4];
    }
  }
  const float rtot = rtotg[b];
  __syncthreads();
  const int p = tid & 15, w = tid >> 4;
  float part = 0.f;
#pragma unroll
  for (int k = 0; k < 8; ++k) {
    const int i = k * 16 + w;
    float E = 0.f;
    if (p < NP) {
      float rf = Rfs[(i + p) * 16 + p];
      float q  = Qs[(143 - i - p) * 16 + (9 - p)];
      E = __builtin_amdgcn_exp2f(rtot - rf - q);
      part += E;
    }
    Es[i * 16 + p] = E;
  }
  rsl[p * 17 + w] = part;
  __syncthreads();
  if (tid < NP) {
    float s = 0.f;
#pragma unroll
    for (int w2 = 0; w2 < 16; ++w2) s += rsl[tid * 17 + w2];
    atomicAdd(&rowsumg[b * 16 + tid], s);
  }
  const int c = tid;
  const float* hb = h + ((size_t)b * CH + c) * T_ + t0;
  float acc[NP];
#pragma unroll
  for (int pp = 0; pp < NP; ++pp) acc[pp] = 0.f;
  for (int t4 = 0; t4 < 32; ++t4) {
    float4 hv = *(const float4*)(hb + t4 * 4);
    float he[4] = {hv.x, hv.y, hv.z, hv.w};
#pragma unroll
    for (int u = 0; u < 4; ++u) {
      const float* ar = &Es[(t4 * 4 + u) * 16];
#pragma unroll
      for (int pp = 0; pp < NP; ++pp) acc[pp] += he[u] * ar[pp];
    }
  }
  float* dst = out3raw + ((size_t)(b * CH + c)) * NP;
#pragma unroll
  for (int pp = 0; pp < NP; ++pp) atomicAdd(dst + pp, acc[pp]);
}

// ---------------- K6a: proj, attn softmax, ind argmax ----------------
__global__ __launch_bounds__(64) void k6a_head(const float* __restrict__ out1w, const float* __restrict__ out2w,
                                               const float* __restrict__ out3raw, const float* __restrict__ rowsumg,
                                               const float* __restrict__ enc_w, const float* __restrict__ enc_b,
                                               const float* __restrict__ sw, float* __restrict__ attn_out,
                                               float* __restrict__ ind_sum) {
  const int b = blockIdx.x;
  const int lane = threadIdx.x;
  float a1 = 0.f, a2[NP], a3[NP];
#pragma unroll
  for (int p = 0; p < NP; ++p) { a2[p] = 0.f; a3[p] = 0.f; }
#pragma unroll
  for (int k = 0; k < 4; ++k) {
    const int c = lane + k * 64;
    const float ew = enc_w[c];
    a1 += out1w[b * CH + c] * ew;
    const float* o2 = out2w + ((size_t)(b * CH + c)) * NP;
    const float* o3 = out3raw + ((size_t)(b * CH + c)) * NP;
#pragma unroll
    for (int p = 0; p < NP; ++p) { a2[p] += o2[p] * ew; a3[p] += o3[p] * ew; }
  }
#pragma unroll
  for (int st = 32; st >= 1; st >>= 1) {
    a1 += __shfl_xor(a1, st);
#pragma unroll
    for (int p = 0; p < NP; ++p) { a2[p] += __shfl_xor(a2[p], st); a3[p] += __shfl_xor(a3[p], st); }
  }
  __shared__ float proj[30];
  __shared__ float indv[90];
  if (lane == 0) {
#pragma unroll
    for (int p = 0; p < NP; ++p) {
      proj[p] = a1;
      proj[10 + p] = a2[p];
      proj[20 + p] = a3[p] / rowsumg[b * 16 + p];
    }
  }
  __syncthreads();
  if (lane < 30) {
    const float pj = proj[lane];
    const float eb = enc_b[0];
    float lg[30];
    float mx = -1e30f;
#pragma unroll
    for (int j = 0; j < 30; ++j) { lg[j] = pj * sw[j] + eb; mx = fmaxf(mx, lg[j]); }
    float ssum = 0.f;
#pragma unroll
    for (int j = 0; j < 30; ++j) { lg[j] = expf(lg[j] - mx); ssum += lg[j]; }
    const float inv = 1.f / ssum;
    float m0 = 0.f, m1 = 0.f, m2 = 0.f;
#pragma unroll
    for (int j = 0; j < 30; ++j) {
      const float av = lg[j] * inv;
      attn_out[(size_t)b * 900 + lane * 30 + j] = av;
      if (j < 10) m0 += av; else if (j < 20) m1 += av; else m2 += av;
    }
    indv[lane] = m0 * 0.1f; indv[30 + lane] = m1 * 0.1f; indv[60 + lane] = m2 * 0.1f;
  }
  __syncthreads();
  if (lane == 0) {
    float best = -1e30f; int bi = 0;
    for (int k = 0; k < 90; ++k) { const float v = indv[k]; if (v > best) { best = v; bi = k; } }
    atomicAdd(ind_sum, (float)bi);
  }
}

// ---------------- K7b: ensemble = concat_out @ attn (reads out2 means at DO_ONE) ----------------
__global__ __launch_bounds__(256) void k7b_ens(const float* __restrict__ out1w, const float* __restrict__ out2w,
                                               const float* __restrict__ out3raw, const float* __restrict__ rowsumg,
                                               const float* __restrict__ attn, float* __restrict__ ens) {
  const int b = blockIdx.x, tid = threadIdx.x;
  __shared__ float at[900];
  __shared__ float s0[30];
  __shared__ float irs[NP];
  for (int k = tid; k < 900; k += 256) at[k] = attn[(size_t)b * 900 + k];
  if (tid < NP) irs[tid] = 1.f / rowsumg[b * 16 + tid];
  __syncthreads();
  if (tid < 30) {
    float s = 0.f;
    for (int i = 0; i < 10; ++i) s += at[i * 30 + tid];
    s0[tid] = s;
  }
  __syncthreads();
  const int c = tid;
  const float o1 = out1w[b * CH + c];
  float o2[NP], o3[NP];
  const float* p2 = out2w + ((size_t)(b * CH + c)) * NP;
  const float* p3 = out3raw + ((size_t)(b * CH + c)) * NP;
#pragma unroll
  for (int p = 0; p < NP; ++p) { o2[p] = p2[p]; o3[p] = p3[p] * irs[p]; }
  float* dst = ens + ((size_t)(b * CH + c)) * 30;
#pragma unroll
  for (int j = 0; j < 30; ++j) {
    float acc = o1 * s0[j];
#pragma unroll
    for (int p = 0; p < NP; ++p) acc += o2[p] * at[(10 + p) * 30 + j] + o3[p] * at[(20 + p) * 30 + j];
    dst[j] = acc;
  }
}

// ---------------- K7a: one = selected branch (in-place: DO_ONE already holds out2 means) ----------------
__global__ __launch_bounds__(256) void k7a_one(const float* __restrict__ out1w, const float* __restrict__ out3raw,
                                               const float* __restrict__ rowsumg, const float* __restrict__ indws,
                                               float* __restrict__ oneb, float* __restrict__ op_out) {
  const int b = blockIdx.x, c = threadIdx.x;
  const float ind = indws[0] * (1.f / 64.f);
  const int op = ind < 0.6f ? 0 : (ind < 1.6f ? 1 : 2);
  if (b == 0 && c == 0) op_out[0] = (float)op;
  float* dst = oneb + ((size_t)(b * CH + c)) * NP;
  if (op == 0) {
    const float v = out1w[b * CH + c];
#pragma unroll
    for (int p = 0; p < NP; ++p) dst[p] = v;
  } else if (op == 2) {
    const float* s = out3raw + ((size_t)(b * CH + c)) * NP;
#pragma unroll
    for (int p = 0; p < NP; ++p) dst[p] = s[p] / rowsumg[b * 16 + p];
  }
  // op == 1: DO_ONE already holds out2 means
}

// ---------------- K7c: z1 partial GEMM ----------------
__global__ __launch_bounds__(256) void k7c_z1(const float* __restrict__ one_, const float* __restrict__ w1,
                                              float* __restrict__ z1acc) {
  const int kt = blockIdx.x;
  const int mt = blockIdx.y;
  const int tid = threadIdx.x;
  __shared__ float os[64][65];
  __shared__ float wsl[64][65];
  const int k0 = kt * 64, m0 = mt * 64;
#pragma unroll
  for (int k = 0; k < 4; ++k) {
    int idx = tid + k * 256;
    int r = idx >> 4, q = (idx & 15) * 4;
    float4 v1 = *(const float4*)(one_ + (size_t)r * 2560 + m0 + q);
    os[r][q] = v1.x; os[r][q + 1] = v1.y; os[r][q + 2] = v1.z; os[r][q + 3] = v1.w;
    float4 v2 = *(const float4*)(w1 + (size_t)(k0 + r) * 2560 + m0 + q);
    wsl[r][q] = v2.x; wsl[r][q + 1] = v2.y; wsl[r][q + 2] = v2.z; wsl[r][q + 3] = v2.w;
  }
  __syncthreads();
  const int bg = tid >> 4, kg = tid & 15;
  float acc[4][4];
#pragma unroll
  for (int i = 0; i < 4; ++i)
#pragma unroll
    for (int j = 0; j < 4; ++j) acc[i][j] = 0.f;
  for (int m = 0; m < 64; ++m) {
    float ov[4], wv[4];
#pragma unroll
    for (int i = 0; i < 4; ++i) { ov[i] = os[bg * 4 + i][m]; wv[i] = wsl[kg * 4 + i][m]; }
#pragma unroll
    for (int i = 0; i < 4; ++i)
#pragma unroll
      for (int j = 0; j < 4; ++j) acc[i][j] += ov[i] * wv[j];
  }
#pragma unroll
  for (int i = 0; i < 4; ++i)
#pragma unroll
    for (int j = 0; j < 4; ++j)
      atomicAdd(&z1acc[(size_t)(bg * 4 + i) * 512 + k0 + kg * 4 + j], acc[i][j]);
}

// ---------------- K7d: z2 partial GEMM ----------------
__global__ __launch_bounds__(256) void k7d_z2(const float* __restrict__ z1acc, const float* __restrict__ db1,
                                              const float* __restrict__ w2, float* __restrict__ z2acc) {
  const int kt = blockIdx.x;
  const int mt = blockIdx.y;
  const int tid = threadIdx.x;
  __shared__ float os[64][65];
  __shared__ float wsl[64][65];
  const int k0 = kt * 64, m0 = mt * 64;
#pragma unroll
  for (int k = 0; k < 4; ++k) {
    int idx = tid + k * 256;
    int r = idx >> 4, q = (idx & 15) * 4;
    float4 v1 = *(const float4*)(z1acc + (size_t)r * 512 + m0 + q);
    float4 bv = *(const float4*)(db1 + m0 + q);
    os[r][q] = fmaxf(v1.x + bv.x, 0.f); os[r][q + 1] = fmaxf(v1.y + bv.y, 0.f);
    os[r][q + 2] = fmaxf(v1.z + bv.z, 0.f); os[r][q + 3] = fmaxf(v1.w + bv.w, 0.f);
    float4 v2 = *(const float4*)(w2 + (size_t)(k0 + r) * 512 + m0 + q);
    wsl[r][q] = v2.x; wsl[r][q + 1] = v2.y; wsl[r][q + 2] = v2.z; wsl[r][q + 3] = v2.w;
  }
  __syncthreads();
  const int bg = tid >> 4, kg = tid & 15;
  float acc[4][4];
#pragma unroll
  for (int i = 0; i < 4; ++i)
#pragma unroll
    for (int j = 0; j < 4; ++j) acc[i][j] = 0.f;
  for (int m = 0; m < 64; ++m) {
    float ov[4], wv[4];
#pragma unroll
    for (int i = 0; i < 4; ++i) { ov[i] = os[bg * 4 + i][m]; wv[i] = wsl[kg * 4 + i][m]; }
#pragma unroll
    for (int i = 0; i < 4; ++i)
#pragma unroll
      for (int j = 0; j < 4; ++j) acc[i][j] += ov[i] * wv[j];
  }
#pragma unroll
  for (int i = 0; i < 4; ++i)
#pragma unroll
    for (int j = 0; j < 4; ++j)
      atomicAdd(&z2acc[(size_t)(bg * 4 + i) * 1024 + k0 + kg * 4 + j], acc[i][j]);
}

// ---------------- K7e: out = relu(z2+b2) @ w3^T + b3 ----------------
__global__ __launch_bounds__(64) void k7e_out(const float* __restrict__ z2acc, const float* __restrict__ db2,
                                              const float* __restrict__ w3, const float* __restrict__ db3,
                                              float* __restrict__ outp) {
  const int b = blockIdx.x, lane = threadIdx.x;
  float acc[NP];
#pragma unroll
  for (int n = 0; n < NP; ++n) acc[n] = 0.f;
  for (int j = lane; j < 1024; j += 64) {
    float zv = z2acc[(size_t)b * 1024 + j] + db2[j];
    zv = fmaxf(zv, 0.f);
#pragma unroll
    for (int n = 0; n < NP; ++n) acc[n] += zv * w3[(size_t)n * 1024 + j];
  }
#pragma unroll
  for (int n = 0; n < NP; ++n)
#pragma unroll
    for (int st = 32; st >= 1; st >>= 1) acc[n] += __shfl_xor(acc[n], st);
  if (lane == 0) {
#pragma unroll
    for (int n = 0; n < NP; ++n) outp[b * NP + n] = acc[n] + db3[n];
  }
}

// ---------------- launch ----------------
extern "C" void kernel_launch(void* const* d_in, const int* in_sizes, int n_in,
                              void* d_out, int out_size, void* d_ws, size_t ws_size,
                              hipStream_t stream) {
  (void)in_sizes; (void)n_in; (void)out_size; (void)ws_size;
  const float* x      = (const float*)d_in[0];
  const float* conv_w = (const float*)d_in[1];
  const float* conv_b = (const float*)d_in[2];
  const float* protos = (const float*)d_in[3];
  const float* sw     = (const float*)d_in[4];
  const float* enc_w  = (const float*)d_in[5];
  const float* enc_b  = (const float*)d_in[6];
  const float* dw1    = (const float*)d_in[7];
  const float* db1    = (const float*)d_in[8];
  const float* dw2    = (const float*)d_in[9];
  const float* db2    = (const float*)d_in[10];
  const float* dw3    = (const float*)d_in[11];
  const float* db3    = (const float*)d_in[12];
  float* out = (float*)d_out;
  float* ws  = (float*)d_ws;

  float* D2g     = ws + OFF_D2;
  float* Rfg     = ws + OFF_RF;
  float* Qg      = ws + OFF_Q;
  unsigned* bkey = (unsigned*)(ws + OFF_BK);
  float* z1acc   = ws + OFF_BK;            // aliases bkey (dead after k4)
  float* z2acc   = ws + OFF_BK + 32768;
  float* rowsumg = ws + OFF_RS;
  float* rtotg   = ws + OFF_RT;
  float* out1w   = ws + OFF_O1;
  float* out3raw = ws + OFF_O3;
  float* indws   = ws + OFF_IND;
  float* h       = out + DO_H;
  float* out2w   = out + DO_ONE;           // raw sums -> means -> "one"

  hipMemsetAsync(ws + OFF_BK, 0xFF, (size_t)64 * BKROWS * sizeof(float), stream);   // diag-min keys
  hipMemsetAsync(ws + OFF_RS, 0, (WS_END - OFF_RS) * sizeof(float), stream);        // rowsum/out3/ind
  hipMemsetAsync(out + DO_ONE, 0, (size_t)163840 * sizeof(float), stream);          // out2 raw accum

  k1_conv<<<dim3(16, 4, 64), 256, 0, stream>>>(x, conv_w, conv_b, h, out2w);
  k2_d2<<<dim3(8, 64), 256, 0, stream>>>(h, protos, D2g, bkey);
  k3b_fin<<<64, 256, 0, stream>>>(out2w, out1w, bkey);
  k4_dp<<<16, 64, 0, stream>>>(D2g, (const float*)bkey, Rfg, Qg, rtotg);
  hipMemsetAsync(z1acc, 0, (size_t)98304 * sizeof(float), stream);                  // z1+z2 (bkey dead)
  k5_out3<<<dim3(16, 64), 256, 0, stream>>>(h, Rfg, Qg, rtotg, out3raw, rowsumg);
  k6a_head<<<64, 64, 0, stream>>>(out1w, out2w, out3raw, rowsumg, enc_w, enc_b, sw,
                                  out + DO_ATT, indws);
  k7b_ens<<<64, 256, 0, stream>>>(out1w, out2w, out3raw, rowsumg, out + DO_ATT, out + DO_ENS);
  k7a_one<<<64, 256, 0, stream>>>(out1w, out3raw, rowsumg, indws, out + DO_ONE, out + DO_OP);
  k7c_z1<<<dim3(8, 40), 256, 0, stream>>>(out + DO_ONE, dw1, z1acc);
  k7d_z2<<<dim3(16, 8), 256, 0, stream>>>(z1acc, db1, dw2, z2acc);
  k7e_out<<<64, 64, 0, stream>>>(z2acc, db2, dw3, db3, out + DO_OUT);
}

// Round 6
// 629.212 us; speedup vs baseline: 1.1975x; 1.1975x over previous
//
#include <hip/hip_runtime.h>

// ---------------- constants ----------------
#define B_    64
#define CIN   64
#define CH    256
#define T_    2048
#define NP    10
#define INVLN2 1.44269504088896340736f
#define INFV  1e10f
#define FPAD  16          // front-pad rows of diag buffers
#define DROWS 2088        // diag rows incl pads
#define SDIAG 33408       // DROWS*16 per batch
#define BFPAD 16
#define BKROWS 2096       // per-batch b rows incl pads

// d_out element offsets (float32)
static const size_t DO_H   = 0;
static const size_t DO_OUT = 33554432;
static const size_t DO_ENS = 33555072;
static const size_t DO_ONE = 34046592;   // holds out2 raw sums -> means -> "one"
static const size_t DO_OP  = 34210432;
static const size_t DO_ATT = 34210433;

// d_ws element offsets (float32)
static const size_t OFF_D2 = 0;          // [64][2088][16] diag layout
static const size_t OFF_RF = 2138112;    // [64][2088][16] forward R'
static const size_t OFF_Q  = 4276224;    // [64][2088][16] reverse Q = R~' - D'
static const size_t OFF_BK = 6414336;    // [64][2096] diag-min keys -> floats; later z1/z2
static const size_t OFF_RS = 6548480;    // [64][16] rowsums (zeroed)
static const size_t OFF_RT = 6549504;    // [64] rtot'
static const size_t OFF_O1 = 6549568;    // [64][256] out1 means
static const size_t OFF_O3 = 6565952;    // [64][256][10] out3 raw (zeroed)
static const size_t OFF_IND= 6729792;    // [0]=ind sum (zeroed)
static const size_t WS_END = 6729808;    // 26.92 MB

// lane i <- lane i-1 within 16-lane row; shifted-in lanes get INFV
__device__ __forceinline__ float dpp_shr1_inf(float x) {
  return __int_as_float(__builtin_amdgcn_update_dpp(
      __float_as_int(INFV), __float_as_int(x), 0x111, 0xf, 0xf, false));
}
// lane i <- lane i-1 within 16-lane row; shifted-in lanes get 0
__device__ __forceinline__ float dpp_shr1_z(float x) {
  return __int_as_float(__builtin_amdgcn_update_dpp(0, __float_as_int(x), 0x111, 0xf, 0xf, true));
}
// 16-lane row prefix sum; lane 15 of each row holds the row total
__device__ __forceinline__ float row_prefix_sum16(float v) {
  v += __int_as_float(__builtin_amdgcn_update_dpp(0, __float_as_int(v), 0x111, 0xf, 0xf, true));
  v += __int_as_float(__builtin_amdgcn_update_dpp(0, __float_as_int(v), 0x112, 0xf, 0xf, true));
  v += __int_as_float(__builtin_amdgcn_update_dpp(0, __float_as_int(v), 0x114, 0xf, 0xf, true));
  v += __int_as_float(__builtin_amdgcn_update_dpp(0, __float_as_int(v), 0x118, 0xf, 0xf, true));
  return v;
}
__device__ __forceinline__ unsigned fkey(float f) {
  unsigned u = __float_as_uint(f);
  return (u & 0x80000000u) ? ~u : (u | 0x80000000u);
}

// ---------------- K1: h = relu(conv_w @ x + b), fused STP raw segment sums ----------------
__global__ __launch_bounds__(256) void k1_conv(const float* __restrict__ x, const float* __restrict__ w,
                                               const float* __restrict__ bias, float* __restrict__ h,
                                               float* __restrict__ out2w) {
  const int tt = blockIdx.x, ot = blockIdx.y, b = blockIdx.z;
  const int tid = threadIdx.x;
  __shared__ float xs[64][132];
  __shared__ float wt[64][64];
  const int t0 = tt * 128, o0 = ot * 64;
  {
    const float* xb = x + ((size_t)b * CIN) * T_ + t0;
#pragma unroll
    for (int k = 0; k < 8; ++k) {
      int idx = tid + k * 256;
      int c = idx >> 5, q = idx & 31;
      float4 v = *(const float4*)(xb + (size_t)c * T_ + q * 4);
      *(float4*)(&xs[c][q * 4]) = v;
    }
#pragma unroll
    for (int k = 0; k < 4; ++k) {
      int idx = tid + k * 256;
      int o = idx >> 4, c4 = (idx & 15) * 4;
      float4 v = *(const float4*)(w + (size_t)(o0 + o) * 64 + c4);
      wt[c4 + 0][o] = v.x; wt[c4 + 1][o] = v.y; wt[c4 + 2][o] = v.z; wt[c4 + 3][o] = v.w;
    }
  }
  __syncthreads();
  const int og = tid >> 4, tg = tid & 15;
  float acc[4][8];
#pragma unroll
  for (int i = 0; i < 4; ++i)
#pragma unroll
    for (int j = 0; j < 8; ++j) acc[i][j] = 0.f;
  for (int c = 0; c < 64; ++c) {
    float a0 = wt[c][og * 4 + 0], a1 = wt[c][og * 4 + 1], a2 = wt[c][og * 4 + 2], a3 = wt[c][og * 4 + 3];
    float xv[8];
#pragma unroll
    for (int j = 0; j < 8; ++j) xv[j] = xs[c][tg * 8 + j];
#pragma unroll
    for (int j = 0; j < 8; ++j) {
      acc[0][j] += a0 * xv[j]; acc[1][j] += a1 * xv[j];
      acc[2][j] += a2 * xv[j]; acc[3][j] += a3 * xv[j];
    }
  }
  // segment geometry
  const int tb = t0 + tg * 8;
  int s_lo = tb / 204; if (s_lo > 9) s_lo = 9;
  int s_hi = (tb + 7) / 204; if (s_hi > 9) s_hi = 9;
  const int cross = (s_hi > s_lo) ? ((s_lo + 1) * 204 - tb) : 8;
  int sblock = t0 / 204; if (sblock > 9) sblock = 9;
  const bool crossB = (sblock < 9) && ((sblock + 1) * 204 < t0 + 128);

  float* hb = h + ((size_t)b * CH + o0) * T_ + t0;
#pragma unroll
  for (int i = 0; i < 4; ++i) {
    const float bv = bias[o0 + og * 4 + i];
    float vs[8];
#pragma unroll
    for (int j = 0; j < 8; ++j) vs[j] = fmaxf(acc[i][j] + bv, 0.f);
    float4 v0, v1;
    v0.x = vs[0]; v0.y = vs[1]; v0.z = vs[2]; v0.w = vs[3];
    v1.x = vs[4]; v1.y = vs[5]; v1.z = vs[6]; v1.w = vs[7];
    *(float4*)(&hb[(size_t)(og * 4 + i) * T_ + tg * 8]) = v0;
    *(float4*)(&hb[(size_t)(og * 4 + i) * T_ + tg * 8 + 4]) = v1;
    float sumA = 0.f, sumB = 0.f;
#pragma unroll
    for (int j = 0; j < 8; ++j) { if (j < cross) sumA += vs[j]; else sumB += vs[j]; }
    float cLo = ((s_lo == sblock) ? sumA : 0.f) + ((s_hi == sblock) ? sumB : 0.f);
    float cHi = ((s_lo == sblock + 1) ? sumA : 0.f) + ((s_hi == sblock + 1) ? sumB : 0.f);
    float rLo = row_prefix_sum16(cLo);
    float rHi = row_prefix_sum16(cHi);
    if (tg == 15) {
      float* o2p = out2w + ((size_t)(b * CH + o0 + og * 4 + i)) * NP;
      atomicAdd(o2p + sblock, rLo);
      if (crossB) atomicAdd(o2p + sblock + 1, rHi);
    }
  }
}

// ---------------- K2: D2diag[d][p] (log2-scaled) + per-diagonal min keys ----------------
__global__ __launch_bounds__(256) void k2_d2(const float* __restrict__ h, const float* __restrict__ protos,
                                             float* __restrict__ D2g, unsigned* __restrict__ bkey) {
  const int tt = blockIdx.x, b = blockIdx.y, tid = threadIdx.x;
  __shared__ float pl[2560];
  __shared__ float pn[NP];
  __shared__ unsigned smin[272];
#pragma unroll
  for (int k = 0; k < 10; ++k) pl[tid + k * 256] = protos[tid + k * 256];
  for (int i = tid; i < 272; i += 256) smin[i] = 0xFFFFFFFFu;
  __syncthreads();
  if (tid < NP) {
    float s = 0.f;
    for (int c = 0; c < CH; ++c) { float v = pl[c * NP + tid]; s += v * v; }
    pn[tid] = s;
  }
  __syncthreads();
  const int t0 = tt * 256;
  const int t = t0 + tid;
  const float* hb = h + (size_t)b * CH * T_ + t;
  float hn = 0.f, ph[NP];
#pragma unroll
  for (int p = 0; p < NP; ++p) ph[p] = 0.f;
  for (int c = 0; c < CH; ++c) {
    float hv = hb[(size_t)c * T_];
    hn += hv * hv;
#pragma unroll
    for (int p = 0; p < NP; ++p) ph[p] += pl[c * NP + p] * hv;
  }
  float* dst = D2g + (size_t)b * SDIAG + FPAD * 16;
#pragma unroll
  for (int p = 0; p < NP; ++p) {
    float dv = (pn[p] + hn - 2.f * ph[p]) * INVLN2;
    dst[(t + p) * 16 + p] = dv;
    atomicMin(&smin[tid + p], fkey(dv));
  }
  __syncthreads();
  unsigned* bk = bkey + (size_t)b * BKROWS + BFPAD + t0;
  for (int i = tid; i < 265; i += 256) atomicMin(&bk[i], smin[i]);
}

// ---------------- K3b: decode b keys; finalize out1/out2 means ----------------
__global__ __launch_bounds__(256) void k3b_fin(float* __restrict__ out2w, float* __restrict__ out1w,
                                               unsigned* __restrict__ bkey) {
  const int b = blockIdx.x, o = threadIdx.x;
  unsigned* bk = bkey + (size_t)b * BKROWS;
  for (int i = o; i < BKROWS; i += 256) {
    unsigned u = bk[i];
    float f = (u & 0x80000000u) ? __uint_as_float(u ^ 0x80000000u) : __uint_as_float(~u);
    ((float*)bk)[i] = f;
  }
  float* p = out2w + ((size_t)(b * CH + o)) * NP;
  float vals[NP], tot = 0.f;
#pragma unroll
  for (int s = 0; s < NP; ++s) { vals[s] = p[s]; tot += vals[s]; }
  out1w[b * CH + o] = tot * (1.f / 2048.f);
#pragma unroll
  for (int s = 0; s < 9; ++s) p[s] = vals[s] * (1.f / 204.f);
  p[9] = vals[9] * (1.f / 212.f);
}

// ---------------- K4: bidirectional soft-DTW DP, phase-split for ILP ----------------
// 32 blocks x 1 wave; lane groups: {0: fwd b0, 1: rev b0, 2: fwd b1, 3: rev b1}.
// (m,e) rep: y = m - log2(e); per-diagonal baseline b_d subtracted.
// Main-loop 8-step blocks are phase-split: A) m-recurrence (dpp->min3->add, saving g's),
// B) bulk exp2, C) e-recurrence (dpp->mul->fma->fma), D) bulk log2 + stores. Identical
// arithmetic to the fused form; reordering detaches trans ops & stores from the chains
// so the in-order wave doesn't serialize on log2/store every step.
__global__ __launch_bounds__(64, 1) void k4_dp(const float* __restrict__ D2g, const float* __restrict__ bg,
                                               float* __restrict__ Rfg, float* __restrict__ Qg,
                                               float* __restrict__ rtotg) {
  const int l = threadIdx.x;
  const int grp = l >> 4, lr = l & 15;
  const bool isB = (grp & 1) != 0;
  const int bat = (blockIdx.x << 1) + (grp >> 1);
  const int elem  = isB ? (9 - lr) : lr;
  const int dstep = isB ? -16 : 16;
  const int bstep = isB ? -1 : 1;
  const int ld0   = isB ? (FPAD + 2056) * 16 : FPAD * 16;
  const int lb0   = isB ? (BFPAD + 2056) : BFPAD;

  const float* pD = D2g + (size_t)bat * SDIAG + ld0 + elem;
  const float* pB = bg + (size_t)bat * BKROWS + lb0;
  float* pS = (isB ? Qg : Rfg) + (size_t)bat * SDIAG + FPAD * 16 + lr;

  float m1, e1, amP, aeP, bP;
  // ---- d = 0 ----
  {
    float D0 = pD[0], b0 = pB[0];
    m1 = (lr == 0) ? (D0 - b0) : INFV; e1 = 1.f;
    amP = INFV; aeP = 1.f; bP = b0;
    pS[0] = m1;
  }
  // ---- prologue d = 1..15 (masked, fused steps) ----
#pragma unroll
  for (int d = 1; d < 16; ++d) {
    pD += dstep; pB += bstep;
    float Dv = pD[0], bv = pB[0];
    float cD = Dv - bv;
    float a_m = dpp_shr1_inf(m1);
    float a_e = dpp_shr1_z(e1);
    float c_m = amP - bP;
    float mt = fminf(fminf(a_m, m1), c_m);
    float e = __builtin_amdgcn_exp2f(mt - a_m) * a_e
            + __builtin_amdgcn_exp2f(mt - m1) * e1
            + __builtin_amdgcn_exp2f(mt - c_m) * aeP;
    float mn = mt + cD;
    float y = mn - __builtin_amdgcn_logf(e);
    amP = a_m; aeP = a_e; bP = bv;
    m1 = mn; e1 = e;
    if (lr > d) { m1 = INFV; e1 = 1.f; }
    pS[d * 16] = isB ? (y - cD) : y;
  }
  // ---- prefill cur (d=16..23) and n1 (d=24..31) ----
  float cA[8], bA[8], n1D[8], n1B[8];
#pragma unroll
  for (int j = 0; j < 8; ++j) {
    pD += dstep; pB += bstep;
    float Dv = pD[0], bv = pB[0];
    cA[j] = Dv - bv; bA[j] = bv;
  }
#pragma unroll
  for (int j = 0; j < 8; ++j) {
    pD += dstep; pB += bstep;
    n1D[j] = pD[0]; n1B[j] = pB[0];
  }
  pD += dstep; pB += bstep;            // first in-loop prefetch reads d=32
  pS += 256;                           // store base -> d=16

  // ---- main loop d = 16..2055, blocks of 8, distance-2 prefetch, phase-split ----
#pragma unroll 1
  for (int d0 = 16; d0 <= 2048; d0 += 8) {
    // prefetch block d0+16
    float n2D[8], n2B[8];
    if (d0 <= 2032) {
#pragma unroll
      for (int j = 0; j < 8; ++j) {
        n2D[j] = pD[0]; n2B[j] = pB[0];
        pD += dstep; pB += bstep;
      }
    }
    // Phase A: m-recurrence (tight chain: dpp -> min3 -> add)
    float g1[8], g2[8], g3[8], msv[8];
#pragma unroll
    for (int j = 0; j < 8; ++j) {
      float a_m = dpp_shr1_inf(m1);
      float c_m = amP - bP;
      float mt = fminf(fminf(a_m, m1), c_m);
      g1[j] = mt - a_m; g2[j] = mt - m1; g3[j] = mt - c_m;
      float mn = mt + cA[j];
      amP = a_m; bP = bA[j];
      msv[j] = mn; m1 = mn;
    }
    // Phase B: 24 independent exp2
    float w1[8], w2[8], w3[8];
#pragma unroll
    for (int j = 0; j < 8; ++j) {
      w1[j] = __builtin_amdgcn_exp2f(g1[j]);
      w2[j] = __builtin_amdgcn_exp2f(g2[j]);
      w3[j] = __builtin_amdgcn_exp2f(g3[j]);
    }
    // Phase C: e-recurrence (tight chain: dpp -> mul -> fma -> fma)
    float esv[8];
#pragma unroll
    for (int j = 0; j < 8; ++j) {
      float a_e = dpp_shr1_z(e1);
      float t = w2[j] * e1;
      t = fmaf(w1[j], a_e, t);
      t = fmaf(w3[j], aeP, t);
      aeP = a_e; e1 = t; esv[j] = t;
    }
    // Phase D: 8 independent log2, then y + stores
    float lg[8];
#pragma unroll
    for (int j = 0; j < 8; ++j) lg[j] = __builtin_amdgcn_logf(esv[j]);
#pragma unroll
    for (int j = 0; j < 8; ++j) {
      float y = msv[j] - lg[j];
      y = isB ? (y - cA[j]) : y;
      pS[j * 16] = y;
    }
    pS += 128;
    // rotate prefetch registers
#pragma unroll
    for (int j = 0; j < 8; ++j) {
      cA[j] = n1D[j] - n1B[j]; bA[j] = n1B[j];
      n1D[j] = n2D[j]; n1B[j] = n2B[j];
    }
  }
  // ---- final step d = 2056 (pointers sit exactly at d=2056) ----
  {
    float Dv = pD[0], bv = pB[0];
    float cD = Dv - bv;
    float a_m = dpp_shr1_inf(m1);
    float a_e = dpp_shr1_z(e1);
    float c_m = amP - bP;
    float mt = fminf(fminf(a_m, m1), c_m);
    float e = __builtin_amdgcn_exp2f(mt - a_m) * a_e
            + __builtin_amdgcn_exp2f(mt - m1) * e1
            + __builtin_amdgcn_exp2f(mt - c_m) * aeP;
    float mn = mt + cD;
    float y = mn - __builtin_amdgcn_logf(e);
    float sv = isB ? (y - cD) : y;
    pS[0] = sv;
    if (!isB && lr == 9) rtotg[bat] = sv;
  }
}

// ---------------- K5: E = exp2(rtot - Rf' - Q); rowsums; out3raw GEMM ----------------
__global__ __launch_bounds__(256) void k5_out3(const float* __restrict__ h, const float* __restrict__ Rfg,
                                               const float* __restrict__ Qg, const float* __restrict__ rtotg,
                                               float* __restrict__ out3raw, float* __restrict__ rowsumg) {
  const int tc = blockIdx.x, b = blockIdx.y, tid = threadIdx.x;
  const int t0 = tc * 128;
  __shared__ float Rfs[2304];
  __shared__ float Qs[2304];
  __shared__ float Es[2048];
  __shared__ float rsl[272];
  const float* Rfb = Rfg + (size_t)b * SDIAG + (size_t)(FPAD + t0) * 16;
  const int qlo = 2056 - t0 - 143;
  const float* Qb = Qg + (size_t)b * SDIAG + (size_t)(FPAD + qlo) * 16;
#pragma unroll
  for (int k = 0; k < 3; ++k) {
    int i4 = tid + k * 256;
    if (i4 < 576) {
      ((float4*)Rfs)[i4] = ((const float4*)Rfb)[i4];
      ((float4*)Qs)[i4]  = ((const float4*)Qb)[i4];
    }
  }
  const float rtot = rtotg[b];
  __syncthreads();
  const int p = tid & 15, w = tid >> 4;
  float part = 0.f;
#pragma unroll
  for (int k = 0; k < 8; ++k) {
    const int i = k * 16 + w;
    float E = 0.f;
    if (p < NP) {
      float rf = Rfs[(i + p) * 16 + p];
      float q  = Qs[(143 - i - p) * 16 + (9 - p)];
      E = __builtin_amdgcn_exp2f(rtot - rf - q);
      part += E;
    }
    Es[i * 16 + p] = E;
  }
  rsl[p * 17 + w] = part;
  __syncthreads();
  if (tid < NP) {
    float s = 0.f;
#pragma unroll
    for (int w2 = 0; w2 < 16; ++w2) s += rsl[tid * 17 + w2];
    atomicAdd(&rowsumg[b * 16 + tid], s);
  }
  const int c = tid;
  const float* hb = h + ((size_t)b * CH + c) * T_ + t0;
  float acc[NP];
#pragma unroll
  for (int pp = 0; pp < NP; ++pp) acc[pp] = 0.f;
  for (int t4 = 0; t4 < 32; ++t4) {
    float4 hv = *(const float4*)(hb + t4 * 4);
    float he[4] = {hv.x, hv.y, hv.z, hv.w};
#pragma unroll
    for (int u = 0; u < 4; ++u) {
      const float* ar = &Es[(t4 * 4 + u) * 16];
#pragma unroll
      for (int pp = 0; pp < NP; ++pp) acc[pp] += he[u] * ar[pp];
    }
  }
  float* dst = out3raw + ((size_t)(b * CH + c)) * NP;
#pragma unroll
  for (int pp = 0; pp < NP; ++pp) atomicAdd(dst + pp, acc[pp]);
}

// ---------------- K6a: proj, attn softmax, ind argmax ----------------
__global__ __launch_bounds__(64) void k6a_head(const float* __restrict__ out1w, const float* __restrict__ out2w,
                                               const float* __restrict__ out3raw, const float* __restrict__ rowsumg,
                                               const float* __restrict__ enc_w, const float* __restrict__ enc_b,
                                               const float* __restrict__ sw, float* __restrict__ attn_out,
                                               float* __restrict__ ind_sum) {
  const int b = blockIdx.x;
  const int lane = threadIdx.x;
  float a1 = 0.f, a2[NP], a3[NP];
#pragma unroll
  for (int p = 0; p < NP; ++p) { a2[p] = 0.f; a3[p] = 0.f; }
#pragma unroll
  for (int k = 0; k < 4; ++k) {
    const int c = lane + k * 64;
    const float ew = enc_w[c];
    a1 += out1w[b * CH + c] * ew;
    const float* o2 = out2w + ((size_t)(b * CH + c)) * NP;
    const float* o3 = out3raw + ((size_t)(b * CH + c)) * NP;
#pragma unroll
    for (int p = 0; p < NP; ++p) { a2[p] += o2[p] * ew; a3[p] += o3[p] * ew; }
  }
#pragma unroll
  for (int st = 32; st >= 1; st >>= 1) {
    a1 += __shfl_xor(a1, st);
#pragma unroll
    for (int p = 0; p < NP; ++p) { a2[p] += __shfl_xor(a2[p], st); a3[p] += __shfl_xor(a3[p], st); }
  }
  __shared__ float proj[30];
  __shared__ float indv[90];
  if (lane == 0) {
#pragma unroll
    for (int p = 0; p < NP; ++p) {
      proj[p] = a1;
      proj[10 + p] = a2[p];
      proj[20 + p] = a3[p] / rowsumg[b * 16 + p];
    }
  }
  __syncthreads();
  if (lane < 30) {
    const float pj = proj[lane];
    const float eb = enc_b[0];
    float lg[30];
    float mx = -1e30f;
#pragma unroll
    for (int j = 0; j < 30; ++j) { lg[j] = pj * sw[j] + eb; mx = fmaxf(mx, lg[j]); }
    float ssum = 0.f;
#pragma unroll
    for (int j = 0; j < 30; ++j) { lg[j] = expf(lg[j] - mx); ssum += lg[j]; }
    const float inv = 1.f / ssum;
    float m0 = 0.f, m1 = 0.f, m2 = 0.f;
#pragma unroll
    for (int j = 0; j < 30; ++j) {
      const float av = lg[j] * inv;
      attn_out[(size_t)b * 900 + lane * 30 + j] = av;
      if (j < 10) m0 += av; else if (j < 20) m1 += av; else m2 += av;
    }
    indv[lane] = m0 * 0.1f; indv[30 + lane] = m1 * 0.1f; indv[60 + lane] = m2 * 0.1f;
  }
  __syncthreads();
  if (lane == 0) {
    float best = -1e30f; int bi = 0;
    for (int k = 0; k < 90; ++k) { const float v = indv[k]; if (v > best) { best = v; bi = k; } }
    atomicAdd(ind_sum, (float)bi);
  }
}

// ---------------- K7b: ensemble = concat_out @ attn (reads out2 means at DO_ONE) ----------------
__global__ __launch_bounds__(256) void k7b_ens(const float* __restrict__ out1w, const float* __restrict__ out2w,
                                               const float* __restrict__ out3raw, const float* __restrict__ rowsumg,
                                               const float* __restrict__ attn, float* __restrict__ ens) {
  const int b = blockIdx.x, tid = threadIdx.x;
  __shared__ float at[900];
  __shared__ float s0[30];
  __shared__ float irs[NP];
  for (int k = tid; k < 900; k += 256) at[k] = attn[(size_t)b * 900 + k];
  if (tid < NP) irs[tid] = 1.f / rowsumg[b * 16 + tid];
  __syncthreads();
  if (tid < 30) {
    float s = 0.f;
    for (int i = 0; i < 10; ++i) s += at[i * 30 + tid];
    s0[tid] = s;
  }
  __syncthreads();
  const int c = tid;
  const float o1 = out1w[b * CH + c];
  float o2[NP], o3[NP];
  const float* p2 = out2w + ((size_t)(b * CH + c)) * NP;
  const float* p3 = out3raw + ((size_t)(b * CH + c)) * NP;
#pragma unroll
  for (int p = 0; p < NP; ++p) { o2[p] = p2[p]; o3[p] = p3[p] * irs[p]; }
  float* dst = ens + ((size_t)(b * CH + c)) * 30;
#pragma unroll
  for (int j = 0; j < 30; ++j) {
    float acc = o1 * s0[j];
#pragma unroll
    for (int p = 0; p < NP; ++p) acc += o2[p] * at[(10 + p) * 30 + j] + o3[p] * at[(20 + p) * 30 + j];
    dst[j] = acc;
  }
}

// ---------------- K7a: one = selected branch (in-place: DO_ONE already holds out2 means) ----------------
__global__ __launch_bounds__(256) void k7a_one(const float* __restrict__ out1w, const float* __restrict__ out3raw,
                                               const float* __restrict__ rowsumg, const float* __restrict__ indws,
                                               float* __restrict__ oneb, float* __restrict__ op_out) {
  const int b = blockIdx.x, c = threadIdx.x;
  const float ind = indws[0] * (1.f / 64.f);
  const int op = ind < 0.6f ? 0 : (ind < 1.6f ? 1 : 2);
  if (b == 0 && c == 0) op_out[0] = (float)op;
  float* dst = oneb + ((size_t)(b * CH + c)) * NP;
  if (op == 0) {
    const float v = out1w[b * CH + c];
#pragma unroll
    for (int p = 0; p < NP; ++p) dst[p] = v;
  } else if (op == 2) {
    const float* s = out3raw + ((size_t)(b * CH + c)) * NP;
#pragma unroll
    for (int p = 0; p < NP; ++p) dst[p] = s[p] / rowsumg[b * 16 + p];
  }
  // op == 1: DO_ONE already holds out2 means
}

// ---------------- K7c: z1 partial GEMM ----------------
__global__ __launch_bounds__(256) void k7c_z1(const float* __restrict__ one_, const float* __restrict__ w1,
                                              float* __restrict__ z1acc) {
  const int kt = blockIdx.x;
  const int mt = blockIdx.y;
  const int tid = threadIdx.x;
  __shared__ float os[64][65];
  __shared__ float wsl[64][65];
  const int k0 = kt * 64, m0 = mt * 64;
#pragma unroll
  for (int k = 0; k < 4; ++k) {
    int idx = tid + k * 256;
    int r = idx >> 4, q = (idx & 15) * 4;
    float4 v1 = *(const float4*)(one_ + (size_t)r * 2560 + m0 + q);
    os[r][q] = v1.x; os[r][q + 1] = v1.y; os[r][q + 2] = v1.z; os[r][q + 3] = v1.w;
    float4 v2 = *(const float4*)(w1 + (size_t)(k0 + r) * 2560 + m0 + q);
    wsl[r][q] = v2.x; wsl[r][q + 1] = v2.y; wsl[r][q + 2] = v2.z; wsl[r][q + 3] = v2.w;
  }
  __syncthreads();
  const int bg = tid >> 4, kg = tid & 15;
  float acc[4][4];
#pragma unroll
  for (int i = 0; i < 4; ++i)
#pragma unroll
    for (int j = 0; j < 4; ++j) acc[i][j] = 0.f;
  for (int m = 0; m < 64; ++m) {
    float ov[4], wv[4];
#pragma unroll
    for (int i = 0; i < 4; ++i) { ov[i] = os[bg * 4 + i][m]; wv[i] = wsl[kg * 4 + i][m]; }
#pragma unroll
    for (int i = 0; i < 4; ++i)
#pragma unroll
      for (int j = 0; j < 4; ++j) acc[i][j] += ov[i] * wv[j];
  }
#pragma unroll
  for (int i = 0; i < 4; ++i)
#pragma unroll
    for (int j = 0; j < 4; ++j)
      atomicAdd(&z1acc[(size_t)(bg * 4 + i) * 512 + k0 + kg * 4 + j], acc[i][j]);
}

// ---------------- K7d: z2 partial GEMM ----------------
__global__ __launch_bounds__(256) void k7d_z2(const float* __restrict__ z1acc, const float* __restrict__ db1,
                                              const float* __restrict__ w2, float* __restrict__ z2acc) {
  const int kt = blockIdx.x;
  const int mt = blockIdx.y;
  const int tid = threadIdx.x;
  __shared__ float os[64][65];
  __shared__ float wsl[64][65];
  const int k0 = kt * 64, m0 = mt * 64;
#pragma unroll
  for (int k = 0; k < 4; ++k) {
    int idx = tid + k * 256;
    int r = idx >> 4, q = (idx & 15) * 4;
    float4 v1 = *(const float4*)(z1acc + (size_t)r * 512 + m0 + q);
    float4 bv = *(const float4*)(db1 + m0 + q);
    os[r][q] = fmaxf(v1.x + bv.x, 0.f); os[r][q + 1] = fmaxf(v1.y + bv.y, 0.f);
    os[r][q + 2] = fmaxf(v1.z + bv.z, 0.f); os[r][q + 3] = fmaxf(v1.w + bv.w, 0.f);
    float4 v2 = *(const float4*)(w2 + (size_t)(k0 + r) * 512 + m0 + q);
    wsl[r][q] = v2.x; wsl[r][q + 1] = v2.y; wsl[r][q + 2] = v2.z; wsl[r][q + 3] = v2.w;
  }
  __syncthreads();
  const int bg = tid >> 4, kg = tid & 15;
  float acc[4][4];
#pragma unroll
  for (int i = 0; i < 4; ++i)
#pragma unroll
    for (int j = 0; j < 4; ++j) acc[i][j] = 0.f;
  for (int m = 0; m < 64; ++m) {
    float ov[4], wv[4];
#pragma unroll
    for (int i = 0; i < 4; ++i) { ov[i] = os[bg * 4 + i][m]; wv[i] = wsl[kg * 4 + i][m]; }
#pragma unroll
    for (int i = 0; i < 4; ++i)
#pragma unroll
      for (int j = 0; j < 4; ++j) acc[i][j] += ov[i] * wv[j];
  }
#pragma unroll
  for (int i = 0; i < 4; ++i)
#pragma unroll
    for (int j = 0; j < 4; ++j)
      atomicAdd(&z2acc[(size_t)(bg * 4 + i) * 1024 + k0 + kg * 4 + j], acc[i][j]);
}

// ---------------- K7e: out = relu(z2+b2) @ w3^T + b3 ----------------
__global__ __launch_bounds__(64) void k7e_out(const float* __restrict__ z2acc, const float* __restrict__ db2,
                                              const float* __restrict__ w3, const float* __restrict__ db3,
                                              float* __restrict__ outp) {
  const int b = blockIdx.x, lane = threadIdx.x;
  float acc[NP];
#pragma unroll
  for (int n = 0; n < NP; ++n) acc[n] = 0.f;
  for (int j = lane; j < 1024; j += 64) {
    float zv = z2acc[(size_t)b * 1024 + j] + db2[j];
    zv = fmaxf(zv, 0.f);
#pragma unroll
    for (int n = 0; n < NP; ++n) acc[n] += zv * w3[(size_t)n * 1024 + j];
  }
#pragma unroll
  for (int n = 0; n < NP; ++n)
#pragma unroll
    for (int st = 32; st >= 1; st >>= 1) acc[n] += __shfl_xor(acc[n], st);
  if (lane == 0) {
#pragma unroll
    for (int n = 0; n < NP; ++n) outp[b * NP + n] = acc[n] + db3[n];
  }
}

// ---------------- launch ----------------
extern "C" void kernel_launch(void* const* d_in, const int* in_sizes, int n_in,
                              void* d_out, int out_size, void* d_ws, size_t ws_size,
                              hipStream_t stream) {
  (void)in_sizes; (void)n_in; (void)out_size; (void)ws_size;
  const float* x      = (const float*)d_in[0];
  const float* conv_w = (const float*)d_in[1];
  const float* conv_b = (const float*)d_in[2];
  const float* protos = (const float*)d_in[3];
  const float* sw     = (const float*)d_in[4];
  const float* enc_w  = (const float*)d_in[5];
  const float* enc_b  = (const float*)d_in[6];
  const float* dw1    = (const float*)d_in[7];
  const float* db1    = (const float*)d_in[8];
  const float* dw2    = (const float*)d_in[9];
  const float* db2    = (const float*)d_in[10];
  const float* dw3    = (const float*)d_in[11];
  const float* db3    = (const float*)d_in[12];
  float* out = (float*)d_out;
  float* ws  = (float*)d_ws;

  float* D2g     = ws + OFF_D2;
  float* Rfg     = ws + OFF_RF;
  float* Qg      = ws + OFF_Q;
  unsigned* bkey = (unsigned*)(ws + OFF_BK);
  float* z1acc   = ws + OFF_BK;            // aliases bkey (dead after k4)
  float* z2acc   = ws + OFF_BK + 32768;
  float* rowsumg = ws + OFF_RS;
  float* rtotg   = ws + OFF_RT;
  float* out1w   = ws + OFF_O1;
  float* out3raw = ws + OFF_O3;
  float* indws   = ws + OFF_IND;
  float* h       = out + DO_H;
  float* out2w   = out + DO_ONE;           // raw sums -> means -> "one"

  hipMemsetAsync(ws + OFF_BK, 0xFF, (size_t)64 * BKROWS * sizeof(float), stream);   // diag-min keys
  hipMemsetAsync(ws + OFF_RS, 0, (WS_END - OFF_RS) * sizeof(float), stream);        // rowsum/out3/ind
  hipMemsetAsync(out + DO_ONE, 0, (size_t)163840 * sizeof(float), stream);          // out2 raw accum

  k1_conv<<<dim3(16, 4, 64), 256, 0, stream>>>(x, conv_w, conv_b, h, out2w);
  k2_d2<<<dim3(8, 64), 256, 0, stream>>>(h, protos, D2g, bkey);
  k3b_fin<<<64, 256, 0, stream>>>(out2w, out1w, bkey);
  k4_dp<<<32, 64, 0, stream>>>(D2g, (const float*)bkey, Rfg, Qg, rtotg);
  hipMemsetAsync(z1acc, 0, (size_t)98304 * sizeof(float), stream);                  // z1+z2 (bkey dead)
  k5_out3<<<dim3(16, 64), 256, 0, stream>>>(h, Rfg, Qg, rtotg, out3raw, rowsumg);
  k6a_head<<<64, 64, 0, stream>>>(out1w, out2w, out3raw, rowsumg, enc_w, enc_b, sw,
                                  out + DO_ATT, indws);
  k7b_ens<<<64, 256, 0, stream>>>(out1w, out2w, out3raw, rowsumg, out + DO_ATT, out + DO_ENS);
  k7a_one<<<64, 256, 0, stream>>>(out1w, out3raw, rowsumg, indws, out + DO_ONE, out + DO_OP);
  k7c_z1<<<dim3(8, 40), 256, 0, stream>>>(out + DO_ONE, dw1, z1acc);
  k7d_z2<<<dim3(16, 8), 256, 0, stream>>>(z1acc, db1, dw2, z2acc);
  k7e_out<<<64, 64, 0, stream>>>(z2acc, db2, dw3, db3, out + DO_OUT);
}